// Round 1
// baseline (80.496 us; speedup 1.0000x reference)
//
#include <hip/hip_runtime.h>

// Problem: B=16, S=256, IN=128, OUT=128, HID=512
// Restructured: y[b,o] = sum_{k=h*128+i} M[b,k]*W2flat[k*128+o] + sum_i sx[b,i]*b2[i*128+o]
//   where M[b,h,i] = sum_s h[b,s,h]*x[b,s,i],  h = relu(x@W1+b1)
// then out = y @ Wfc + bfc.

#define NTOK 4096
#define NPART 512

// ws layout (floats):
//   h:    [4096][512]        off 0        size 2097152
//   M:    [16][65536]        off 2097152  size 1048576
//   part: [512][16][128]     off 3145728  size 1048576
//   sxp:  [16][16][128]      off 4194304  size 32768

// ---------- Stage A: h = relu(x @ W1 + b1)  (4096x128 @ 128x512) ----------
__global__ __launch_bounds__(256) void k_hyp1(const float* __restrict__ x,
        const float* __restrict__ W1, const float* __restrict__ b1,
        float* __restrict__ h) {
    __shared__ float As[64][132];   // x tile: 64 tokens x full K=128 (+4 pad)
    __shared__ float Bs[128][68];   // W1 tile: 128 k x 64 hid (+4 pad)
    const int tid = threadIdx.x;
    const int t0 = (blockIdx.x >> 3) * 64;
    const int h0 = (blockIdx.x & 7) * 64;
    {
        const int r = tid >> 5, c4 = (tid & 31) * 4;
        #pragma unroll
        for (int p = 0; p < 8; ++p) {
            const int tl = p * 8 + r;
            *(float4*)&As[tl][c4] = *(const float4*)&x[(t0 + tl) * 128 + c4];
        }
    }
    {
        const int r = tid >> 4, c4 = (tid & 15) * 4;
        #pragma unroll
        for (int p = 0; p < 8; ++p) {
            const int kk = p * 16 + r;
            *(float4*)&Bs[kk][c4] = *(const float4*)&W1[kk * 512 + h0 + c4];
        }
    }
    __syncthreads();
    const int ty = tid >> 4, tx = tid & 15;
    float acc[4][4] = {};
    #pragma unroll 4
    for (int k = 0; k < 128; ++k) {
        float a[4], b[4];
        #pragma unroll
        for (int i = 0; i < 4; ++i) a[i] = As[ty * 4 + i][k];
        #pragma unroll
        for (int j = 0; j < 4; ++j) b[j] = Bs[k][tx * 4 + j];
        #pragma unroll
        for (int i = 0; i < 4; ++i)
            #pragma unroll
            for (int j = 0; j < 4; ++j)
                acc[i][j] += a[i] * b[j];
    }
    #pragma unroll
    for (int i = 0; i < 4; ++i) {
        float4 v; float* vp = (float*)&v;
        #pragma unroll
        for (int j = 0; j < 4; ++j) {
            float t = acc[i][j] + b1[h0 + tx * 4 + j];
            vp[j] = t > 0.f ? t : 0.f;
        }
        *(float4*)&h[(size_t)(t0 + ty * 4 + i) * 512 + h0 + tx * 4] = v;
    }
}

// ---------- Stage B: M[b,h,i] = sum_s h[b,s,h]*x[b,s,i]  (per-b 512x256 @ 256x128) ----------
__global__ __launch_bounds__(256) void k_hyp2(const float* __restrict__ x,
        const float* __restrict__ h, float* __restrict__ M) {
    __shared__ float hs[64][68];
    __shared__ float xs[64][68];
    const int tid = threadIdx.x;
    const int b  = blockIdx.x >> 4;
    const int h0 = ((blockIdx.x >> 1) & 7) * 64;
    const int i0 = (blockIdx.x & 1) * 64;
    const int ty = tid >> 4, tx = tid & 15;
    float acc[4][4] = {};
    for (int s0 = 0; s0 < 256; s0 += 64) {
        __syncthreads();
        {
            const int r = tid >> 4, c4 = (tid & 15) * 4;
            #pragma unroll
            for (int p = 0; p < 4; ++p) {
                const int sl = p * 16 + r;
                *(float4*)&hs[sl][c4] = *(const float4*)&h[(size_t)(b * 256 + s0 + sl) * 512 + h0 + c4];
                *(float4*)&xs[sl][c4] = *(const float4*)&x[(size_t)(b * 256 + s0 + sl) * 128 + i0 + c4];
            }
        }
        __syncthreads();
        #pragma unroll 4
        for (int k = 0; k < 64; ++k) {
            float a[4], c[4];
            #pragma unroll
            for (int i = 0; i < 4; ++i) a[i] = hs[k][ty * 4 + i];
            #pragma unroll
            for (int j = 0; j < 4; ++j) c[j] = xs[k][tx * 4 + j];
            #pragma unroll
            for (int i = 0; i < 4; ++i)
                #pragma unroll
                for (int j = 0; j < 4; ++j)
                    acc[i][j] += a[i] * c[j];
        }
    }
    #pragma unroll
    for (int i = 0; i < 4; ++i) {
        float4 v; float* vp = (float*)&v;
        #pragma unroll
        for (int j = 0; j < 4; ++j) vp[j] = acc[i][j];
        *(float4*)&M[(size_t)b * 65536 + (h0 + ty * 4 + i) * 128 + i0 + tx * 4] = v;
    }
}

// ---------- sx partials: sxp[c][b][i] = sum_{s in chunk c} x[b,s,i] ----------
__global__ __launch_bounds__(128) void k_sxp(const float* __restrict__ x,
        float* __restrict__ sxp) {
    const int b = blockIdx.x >> 4;
    const int c = blockIdx.x & 15;
    const int t = threadIdx.x;
    float acc = 0.f;
    #pragma unroll
    for (int ss = 0; ss < 16; ++ss)
        acc += x[(size_t)(b * 256 + c * 16 + ss) * 128 + t];
    sxp[(c * 16 + b) * 128 + t] = acc;
}

// ---------- Stage C: split-K partials of y = M @ W2flat  (16x65536 @ 65536x128) ----------
__global__ __launch_bounds__(256) void k_hyp3(const float* __restrict__ M,
        const float* __restrict__ W2, float* __restrict__ part) {
    __shared__ float Ms[16][128];
    const int tid = threadIdx.x;
    const int p = blockIdx.x;
    const int k0 = p * 128;
    #pragma unroll
    for (int r = 0; r < 8; ++r) {
        const int flat = r * 256 + tid;
        const int b = flat >> 7, kk = flat & 127;
        Ms[b][kk] = M[(size_t)b * 65536 + k0 + kk];
    }
    __syncthreads();
    const int o = tid & 127, half = tid >> 7;
    float acc[8] = {};
    #pragma unroll 4
    for (int kk = 0; kk < 128; ++kk) {
        const float w = W2[(size_t)(k0 + kk) * 128 + o];
        #pragma unroll
        for (int j = 0; j < 8; ++j)
            acc[j] += Ms[half * 8 + j][kk] * w;
    }
    #pragma unroll
    for (int j = 0; j < 8; ++j)
        part[(size_t)(p * 16 + half * 8 + j) * 128 + o] = acc[j];
}

// ---------- Stage D: reduce partials, add bias term, apply Wfc ----------
__global__ __launch_bounds__(128) void k_hyp4(const float* __restrict__ part,
        const float* __restrict__ sxp, const float* __restrict__ b2,
        const float* __restrict__ Wfc, const float* __restrict__ bfc,
        float* __restrict__ out) {
    __shared__ float sxs[128];
    __shared__ float ys[128];
    const int b = blockIdx.x;
    const int t = threadIdx.x;
    float y = 0.f;
    #pragma unroll 8
    for (int p = 0; p < NPART; ++p)
        y += part[(size_t)(p * 16 + b) * 128 + t];
    float sv = 0.f;
    #pragma unroll
    for (int c = 0; c < 16; ++c)
        sv += sxp[(c * 16 + b) * 128 + t];
    sxs[t] = sv;
    __syncthreads();
    #pragma unroll 8
    for (int i = 0; i < 128; ++i)
        y += sxs[i] * b2[i * 128 + t];
    ys[t] = y;
    __syncthreads();
    float o = bfc[t];
    #pragma unroll 8
    for (int oo = 0; oo < 128; ++oo)
        o += ys[oo] * Wfc[oo * 128 + t];
    out[b * 128 + t] = o;
}

extern "C" void kernel_launch(void* const* d_in, const int* in_sizes, int n_in,
                              void* d_out, int out_size, void* d_ws, size_t ws_size,
                              hipStream_t stream) {
    const float* x   = (const float*)d_in[0];
    const float* W1  = (const float*)d_in[1];
    const float* b1  = (const float*)d_in[2];
    const float* W2  = (const float*)d_in[3];
    const float* b2  = (const float*)d_in[4];
    const float* Wfc = (const float*)d_in[5];
    const float* bfc = (const float*)d_in[6];
    float* ws   = (float*)d_ws;
    float* h    = ws;
    float* M    = ws + 2097152;
    float* part = ws + 3145728;
    float* sxp  = ws + 4194304;
    float* out  = (float*)d_out;

    k_hyp1<<<512, 256, 0, stream>>>(x, W1, b1, h);
    k_sxp <<<256, 128, 0, stream>>>(x, sxp);
    k_hyp2<<<256, 256, 0, stream>>>(x, h, M);
    k_hyp3<<<512, 256, 0, stream>>>(M, W2, part);
    k_hyp4<<<16,  128, 0, stream>>>(part, sxp, b2, Wfc, bfc, out);
}

// Round 3
// 52.658 us; speedup vs baseline: 1.5287x; 1.5287x over previous
//
#include <hip/hip_runtime.h>

// Problem: B=16, S=256, IN=128, OUT=128, HID=512
// Restructured: y[b,o] = sum_{k=h*128+i} M[b,k]*W2flat[k*128+o] + sum_i sx[b,i]*b2[i*128+o]
//   where M[b,h,i] = sum_s h[b,s,h]*x[b,s,i],  h = relu(x@W1+b1)
// then out = y @ Wfc + bfc.

#define NPART 512

// ws layout (floats):
//   h:    [4096][512]        off 0        size 2097152
//   M:    [16][65536]        off 2097152  size 1048576
//   part: [512][16][128]     off 3145728  size 1048576
//   sxp:  [16][16][128]      off 4194304  size 32768
//   y1:   [16][16][128]      off 4227072  size 32768

// ---------- Stage A: h = relu(x @ W1 + b1)  (4096x128 @ 128x512) ----------
__global__ __launch_bounds__(256) void k_hyp1(const float* __restrict__ x,
        const float* __restrict__ W1, const float* __restrict__ b1,
        float* __restrict__ h) {
    __shared__ float As[64][132];   // x tile: 64 tokens x full K=128 (+4 pad)
    __shared__ float Bs[128][68];   // W1 tile: 128 k x 64 hid (+4 pad)
    const int tid = threadIdx.x;
    const int t0 = (blockIdx.x >> 3) * 64;
    const int h0 = (blockIdx.x & 7) * 64;
    {
        const int r = tid >> 5, c4 = (tid & 31) * 4;
        #pragma unroll
        for (int p = 0; p < 8; ++p) {
            const int tl = p * 8 + r;
            *(float4*)&As[tl][c4] = *(const float4*)&x[(t0 + tl) * 128 + c4];
        }
    }
    {
        const int r = tid >> 4, c4 = (tid & 15) * 4;
        #pragma unroll
        for (int p = 0; p < 8; ++p) {
            const int kk = p * 16 + r;
            *(float4*)&Bs[kk][c4] = *(const float4*)&W1[kk * 512 + h0 + c4];
        }
    }
    __syncthreads();
    const int ty = tid >> 4, tx = tid & 15;
    float acc[4][4] = {};
    #pragma unroll 4
    for (int k = 0; k < 128; ++k) {
        float a[4], b[4];
        #pragma unroll
        for (int i = 0; i < 4; ++i) a[i] = As[ty * 4 + i][k];
        #pragma unroll
        for (int j = 0; j < 4; ++j) b[j] = Bs[k][tx * 4 + j];
        #pragma unroll
        for (int i = 0; i < 4; ++i)
            #pragma unroll
            for (int j = 0; j < 4; ++j)
                acc[i][j] += a[i] * b[j];
    }
    #pragma unroll
    for (int i = 0; i < 4; ++i) {
        float4 v; float* vp = (float*)&v;
        #pragma unroll
        for (int j = 0; j < 4; ++j) {
            float t = acc[i][j] + b1[h0 + tx * 4 + j];
            vp[j] = t > 0.f ? t : 0.f;
        }
        *(float4*)&h[(size_t)(t0 + ty * 4 + i) * 512 + h0 + tx * 4] = v;
    }
}

// ---------- Stage B: M[b,h,i] = sum_s h[b,s,h]*x[b,s,i]  (per-b 512x256 @ 256x128) ----------
__global__ __launch_bounds__(256) void k_hyp2(const float* __restrict__ x,
        const float* __restrict__ h, float* __restrict__ M) {
    __shared__ float hs[64][68];
    __shared__ float xs[64][68];
    const int tid = threadIdx.x;
    const int b  = blockIdx.x >> 4;
    const int h0 = ((blockIdx.x >> 1) & 7) * 64;
    const int i0 = (blockIdx.x & 1) * 64;
    const int ty = tid >> 4, tx = tid & 15;
    float acc[4][4] = {};
    for (int s0 = 0; s0 < 256; s0 += 64) {
        __syncthreads();
        {
            const int r = tid >> 4, c4 = (tid & 15) * 4;
            #pragma unroll
            for (int p = 0; p < 4; ++p) {
                const int sl = p * 16 + r;
                *(float4*)&hs[sl][c4] = *(const float4*)&h[(size_t)(b * 256 + s0 + sl) * 512 + h0 + c4];
                *(float4*)&xs[sl][c4] = *(const float4*)&x[(size_t)(b * 256 + s0 + sl) * 128 + i0 + c4];
            }
        }
        __syncthreads();
        #pragma unroll 4
        for (int k = 0; k < 64; ++k) {
            float a[4], c[4];
            #pragma unroll
            for (int i = 0; i < 4; ++i) a[i] = hs[k][ty * 4 + i];
            #pragma unroll
            for (int j = 0; j < 4; ++j) c[j] = xs[k][tx * 4 + j];
            #pragma unroll
            for (int i = 0; i < 4; ++i)
                #pragma unroll
                for (int j = 0; j < 4; ++j)
                    acc[i][j] += a[i] * c[j];
        }
    }
    #pragma unroll
    for (int i = 0; i < 4; ++i) {
        float4 v; float* vp = (float*)&v;
        #pragma unroll
        for (int j = 0; j < 4; ++j) vp[j] = acc[i][j];
        *(float4*)&M[(size_t)b * 65536 + (h0 + ty * 4 + i) * 128 + i0 + tx * 4] = v;
    }
}

// ---------- sx partials: sxp[c][b][i] = sum_{s in chunk c} x[b,s,i] ----------
__global__ __launch_bounds__(128) void k_sxp(const float* __restrict__ x,
        float* __restrict__ sxp) {
    const int b = blockIdx.x >> 4;
    const int c = blockIdx.x & 15;
    const int t = threadIdx.x;
    float acc = 0.f;
    #pragma unroll
    for (int ss = 0; ss < 16; ++ss)
        acc += x[(size_t)(b * 256 + c * 16 + ss) * 128 + t];
    sxp[(c * 16 + b) * 128 + t] = acc;
}

// ---------- Stage C: split-K partials of y = M @ W2flat  (16x65536 @ 65536x128) ----------
__global__ __launch_bounds__(256) void k_hyp3(const float* __restrict__ M,
        const float* __restrict__ W2, float* __restrict__ part) {
    __shared__ float Ms[16][128];
    const int tid = threadIdx.x;
    const int p = blockIdx.x;
    const int k0 = p * 128;
    #pragma unroll
    for (int r = 0; r < 8; ++r) {
        const int flat = r * 256 + tid;
        const int b = flat >> 7, kk = flat & 127;
        Ms[b][kk] = M[(size_t)b * 65536 + k0 + kk];
    }
    __syncthreads();
    const int o = tid & 127, half = tid >> 7;
    float acc[8] = {};
    #pragma unroll 4
    for (int kk = 0; kk < 128; ++kk) {
        const float w = W2[(size_t)(k0 + kk) * 128 + o];
        #pragma unroll
        for (int j = 0; j < 8; ++j)
            acc[j] += Ms[half * 8 + j][kk] * w;
    }
    #pragma unroll
    for (int j = 0; j < 8; ++j)
        part[(size_t)(p * 16 + half * 8 + j) * 128 + o] = acc[j];
}

// ---------- Stage D1: tree-reduce part[512][16][128] -> y1[16][16][128] ----------
__global__ __launch_bounds__(128) void k_red(const float* __restrict__ part,
        float* __restrict__ y1) {
    const int b  = blockIdx.x & 15;
    const int pg = blockIdx.x >> 4;      // 16 groups of 32 partials
    const int t  = threadIdx.x;
    float acc = 0.f;
    #pragma unroll
    for (int pp = 0; pp < 32; ++pp)
        acc += part[(size_t)((pg * 32 + pp) * 16 + b) * 128 + t];
    y1[(pg * 16 + b) * 128 + t] = acc;
}

// ---------- Stage D2: final reduce + b2 term + Wfc + bfc ----------
__global__ __launch_bounds__(512) void k_hyp4(const float* __restrict__ y1,
        const float* __restrict__ sxp, const float* __restrict__ b2,
        const float* __restrict__ Wfc, const float* __restrict__ bfc,
        float* __restrict__ out) {
    __shared__ float sh[4][128];
    __shared__ float sxs[128];
    __shared__ float ysh[128];
    const int b = blockIdx.x;
    const int t = threadIdx.x & 127;
    const int g = threadIdx.x >> 7;     // 4 groups, each takes 1/4 of serial work
    // partial y reduce: each group sums 4 of 16
    float y = 0.f;
    #pragma unroll
    for (int pg = g * 4; pg < g * 4 + 4; ++pg)
        y += y1[(pg * 16 + b) * 128 + t];
    // sx reduce: each group sums 4 of 16 chunks
    float sv = 0.f;
    #pragma unroll
    for (int c = g * 4; c < g * 4 + 4; ++c)
        sv += sxp[(c * 16 + b) * 128 + t];
    sh[g][t] = sv;
    __syncthreads();
    if (g == 0) sxs[t] = sh[0][t] + sh[1][t] + sh[2][t] + sh[3][t];
    __syncthreads();
    // b2 term: y += sum_i sx[i]*b2[i*128+t], i split 4 ways
    #pragma unroll 8
    for (int i = g * 32; i < g * 32 + 32; ++i)
        y += sxs[i] * b2[i * 128 + t];
    sh[g][t] = y;
    __syncthreads();
    if (g == 0) ysh[t] = sh[0][t] + sh[1][t] + sh[2][t] + sh[3][t];
    __syncthreads();
    // Wfc: out[t] = bfc[t] + sum_oo ysh[oo]*Wfc[oo*128+t], oo split 4 ways
    float o = 0.f;
    #pragma unroll 8
    for (int oo = g * 32; oo < g * 32 + 32; ++oo)
        o += ysh[oo] * Wfc[oo * 128 + t];
    sh[g][t] = o;
    __syncthreads();
    if (g == 0)
        out[b * 128 + t] = bfc[t] + sh[0][t] + sh[1][t] + sh[2][t] + sh[3][t];
}

extern "C" void kernel_launch(void* const* d_in, const int* in_sizes, int n_in,
                              void* d_out, int out_size, void* d_ws, size_t ws_size,
                              hipStream_t stream) {
    const float* x   = (const float*)d_in[0];
    const float* W1  = (const float*)d_in[1];
    const float* b1  = (const float*)d_in[2];
    const float* W2  = (const float*)d_in[3];
    const float* b2  = (const float*)d_in[4];
    const float* Wfc = (const float*)d_in[5];
    const float* bfc = (const float*)d_in[6];
    float* ws   = (float*)d_ws;
    float* h    = ws;
    float* M    = ws + 2097152;
    float* part = ws + 3145728;
    float* sxp  = ws + 4194304;
    float* y1   = ws + 4227072;
    float* out  = (float*)d_out;

    k_hyp1<<<512, 256, 0, stream>>>(x, W1, b1, h);
    k_sxp <<<256, 128, 0, stream>>>(x, sxp);
    k_hyp2<<<256, 256, 0, stream>>>(x, h, M);
    k_hyp3<<<512, 256, 0, stream>>>(M, W2, part);
    k_red <<<256, 128, 0, stream>>>(part, y1);
    k_hyp4<<<16,  512, 0, stream>>>(y1, sxp, b2, Wfc, bfc, out);
}